// Round 6
// baseline (293.190 us; speedup 1.0000x reference)
//
#include <hip/hip_runtime.h>

#define S0LEN 8192
#define L1LEN 4099   // (8192+7)/2
#define L2LEN 2053   // (4099+7)/2
#define NROWS 2048
#define NT2   512

// db4 filters (derived from reference _REC_LO)
constexpr float DEC_LO[8] = {
  -0.010597401784997278f,  0.032883011666982945f,  0.030841381835986965f,
  -0.18703481171888114f,  -0.02798376941698385f,   0.6308807679295904f,
   0.7148465705525415f,    0.23037781330885523f };
constexpr float DEC_HI[8] = {
  -0.23037781330885523f,   0.7148465705525415f,   -0.6308807679295904f,
  -0.02798376941698385f,   0.18703481171888114f,   0.030841381835986965f,
  -0.032883011666982945f, -0.010597401784997278f };
constexpr float REC_LO[8] = {
   0.23037781330885523f,   0.7148465705525415f,    0.6308807679295904f,
  -0.02798376941698385f,  -0.18703481171888114f,   0.030841381835986965f,
   0.032883011666982945f, -0.010597401784997278f };
constexpr float REC_HI[8] = {
  -0.010597401784997278f, -0.032883011666982945f,  0.030841381835986965f,
   0.18703481171888114f,  -0.02798376941698385f,  -0.6308807679295904f,
   0.7148465705525415f,   -0.23037781330885523f };

__device__ __forceinline__ int refl(int m, int n) {
  m = (m < 0) ? (-1 - m) : m;
  m = (m >= n) ? (2 * n - 1 - m) : m;
  return m;
}

__device__ __forceinline__ float softf(float c, float t) {
  float m = fmaxf(fabsf(c) - t, 0.0f);
  return copysignf(m, c);
}

// DWT pair (outputs 2p, 2p+1) from 10-float window w = src[4p-6 .. 4p+3],
// fetched as aligned b64 + b128 + b128 (elem idx e2 float2, e4a/e4b float4).
__device__ __forceinline__ void dwt_pair_vec(const float* __restrict__ buf,
                                             int e2, int e4a, int e4b,
                                             float& ae, float& de, float& ao, float& dd) {
  const float2 w01 = reinterpret_cast<const float2*>(buf)[e2];
  const float4 w25 = reinterpret_cast<const float4*>(buf)[e4a];
  const float4 w69 = reinterpret_cast<const float4*>(buf)[e4b];
  const float w[10] = {w01.x, w01.y, w25.x, w25.y, w25.z, w25.w,
                       w69.x, w69.y, w69.z, w69.w};
  ae = de = ao = dd = 0.f;
#pragma unroll
  for (int q = 0; q < 8; ++q) {   // out[i] += DEC[7-q] * x[2i-6+q]
    ae = fmaf(DEC_LO[7 - q], w[q],     ae);
    de = fmaf(DEC_HI[7 - q], w[q],     de);
    ao = fmaf(DEC_LO[7 - q], w[q + 2], ao);
    dd = fmaf(DEC_HI[7 - q], w[q + 2], dd);
  }
}

// scalar single output i with symmetric reflection; buf holds x[gbase..]
__device__ __forceinline__ void dwt_scalar(const float* __restrict__ buf, int gbase,
                                           int i, int n, float& a, float& d) {
  a = d = 0.f;
#pragma unroll
  for (int q = 0; q < 8; ++q) {
    const float v = buf[refl(2 * i - 6 + q, n) - gbase];
    a = fmaf(DEC_LO[7 - q], v, a);
    d = fmaf(DEC_HI[7 - q], v, d);
  }
}

// iDWT quad: outputs (4q..4q+3) from w = a[2q..2q+4], v = d[2q..2q+4]
__device__ __forceinline__ float4 idwt_quad(const float* __restrict__ w,
                                            const float* __restrict__ v) {
  float4 o; float acc;
  acc = 0.f;
#pragma unroll
  for (int u = 0; u < 4; ++u) { acc = fmaf(w[3-u], REC_LO[2*u],   acc); acc = fmaf(v[3-u], REC_HI[2*u],   acc); }
  o.x = acc;
  acc = 0.f;
#pragma unroll
  for (int u = 0; u < 4; ++u) { acc = fmaf(w[3-u], REC_LO[2*u+1], acc); acc = fmaf(v[3-u], REC_HI[2*u+1], acc); }
  o.y = acc;
  acc = 0.f;
#pragma unroll
  for (int u = 0; u < 4; ++u) { acc = fmaf(w[4-u], REC_LO[2*u],   acc); acc = fmaf(v[4-u], REC_HI[2*u],   acc); }
  o.z = acc;
  acc = 0.f;
#pragma unroll
  for (int u = 0; u < 4; ++u) { acc = fmaf(w[4-u], REC_LO[2*u+1], acc); acc = fmaf(v[4-u], REC_HI[2*u+1], acc); }
  o.w = acc;
  return o;
}

// ---- Fused kernel: gather x(b,:,f) -> denoise in LDS -> scatter out(b,:,f) ----
// Block mapping groups all 64 f of a batch onto ONE XCD (xcd = blockIdx%8
// round-robin): b = (i&7) + 8*(i>>9), f = (i>>3)&63. Each 128B line of x/out
// serves 32 co-resident rows via that XCD's L2 (2MB/batch < 4MB L2).
__global__ void __launch_bounds__(NT2, 6)
k_denoise_fused(const float* __restrict__ x, float* __restrict__ out) {
  const int i   = blockIdx.x;
  const int f   = (i >> 3) & 63;
  const int b   = (i & 7) + 8 * (i >> 9);
  const float* xg = x   + (size_t)b * S0LEN * 64 + f;   // stride-64 gather base
  float*       og = out + (size_t)b * S0LEN * 64 + f;

  __shared__ alignas(16) float X[4112];   // x chunk; later a2[0..2052] | d2 @2056..4108
  __shared__ alignas(16) float A[4100];   // a1; later rec1[0..4098]
  __shared__ alignas(16) float D[4100];   // d1 (raw; soft applied on the fly)
  __shared__ unsigned hist[1024];         // 4 histograms (wave-pairs)
  __shared__ unsigned wsum[4];
  __shared__ int sh_bin, sh_k;
  const int t = threadIdx.x;

  // chunk0 gather: X[j] = x[b, j, f], j in [0, 4108)
  for (int j = t; j < 4108; j += NT2) X[j] = xg[(size_t)j * 64];
  __syncthreads();

  // DWT1 chunk0: pairs p=0..1023 -> outputs 0..2047 (vector for p>=2)
  for (int p = t; p < 1024; p += NT2) {
    float ae, de, ao, dd;
    if (p >= 2) dwt_pair_vec(X, 2 * p - 3, p - 1, p, ae, de, ao, dd);
    else { dwt_scalar(X, 0, 2 * p, S0LEN, ae, de); dwt_scalar(X, 0, 2 * p + 1, S0LEN, ao, dd); }
    reinterpret_cast<float2*>(A)[p] = make_float2(ae, ao);
    reinterpret_cast<float2*>(D)[p] = make_float2(de, dd);
  }
  __syncthreads();

  // chunk1 gather: X[j] = x[b, 4088+j, f], j in [0, 4104)  (base 4088 as before)
  for (int j = t; j < 4104; j += NT2) X[j] = xg[(size_t)(4088 + j) * 64];
  __syncthreads();

  // DWT1 chunk1: pairs p=1024..2048 -> outputs 2048..4097 (vector for p<2048), + single 4098
  for (int p0 = t; p0 < 1025; p0 += NT2) {
    const int p = 1024 + p0;
    float ae, de, ao, dd;
    if (p < 2048) dwt_pair_vec(X, 2 * p - 2047, p - 1023, p - 1022, ae, de, ao, dd);
    else { dwt_scalar(X, 4088, 2 * p, S0LEN, ae, de); dwt_scalar(X, 4088, 2 * p + 1, S0LEN, ao, dd); }
    reinterpret_cast<float2*>(A)[p] = make_float2(ae, ao);
    reinterpret_cast<float2*>(D)[p] = make_float2(de, dd);
  }
  if (t == 0) {
    float a, d; dwt_scalar(X, 4088, 4098, S0LEN, a, d);
    A[4098] = a; D[4098] = d;
  }
  __syncthreads();

  // DWT2: A(4099) -> a2=X[0..2052], d2=X[2056..4108]; pairs 0..1025 (vector 2..1023) + single 2052
  for (int p = t; p < 1026; p += NT2) {
    float ae, de, ao, dd;
    if (p >= 2 && p <= 1023) dwt_pair_vec(A, 2 * p - 3, p - 1, p, ae, de, ao, dd);
    else { dwt_scalar(A, 0, 2 * p, L1LEN, ae, de); dwt_scalar(A, 0, 2 * p + 1, L1LEN, ao, dd); }
    reinterpret_cast<float2*>(X)[p] = make_float2(ae, ao);
    reinterpret_cast<float2*>(X)[1028 + p] = make_float2(de, dd);
  }
  if (t == 1) {
    float a, d; dwt_scalar(A, 0, 2052, L1LEN, a, d);
    X[2052] = a; X[2056 + 2052] = d;
  }
  __syncthreads();

  // exact median of |D| (4099 elems, 0-indexed rank 2049), 4x radix-256 select
  unsigned prefval = 0u, himask = 0u;
  int kk = 2049;
  for (int pass = 0; pass < 4; ++pass) {
    const int shift = 24 - 8 * pass;
    for (int j = t; j < 1024; j += NT2) hist[j] = 0u;
    __syncthreads();
    unsigned* myh = hist + ((t >> 7) << 8);   // wave-pair private histogram
    for (int j = t; j < L1LEN; j += NT2) {
      const unsigned u = __float_as_uint(fabsf(D[j]));
      if ((u & himask) == prefval) atomicAdd(&myh[(u >> shift) & 255u], 1u);
    }
    __syncthreads();
    unsigned c = 0u, incl = 0u;
    if (t < 256) {
      c = hist[t] + hist[t + 256] + hist[t + 512] + hist[t + 768];
      incl = c;
#pragma unroll
      for (int dlt = 1; dlt < 64; dlt <<= 1) {
        const unsigned nn = __shfl_up(incl, dlt, 64);
        if ((t & 63) >= dlt) incl += nn;
      }
      if ((t & 63) == 63) wsum[t >> 6] = incl;
    }
    __syncthreads();
    if (t < 256) {
      unsigned base = 0u;
      for (int w = 0; w < (t >> 6); ++w) base += wsum[w];
      incl += base;
      if ((unsigned)kk < incl && (unsigned)kk >= incl - c) {
        sh_bin = t; sh_k = kk - (int)(incl - c);
      }
    }
    __syncthreads();
    prefval |= ((unsigned)sh_bin) << shift;
    himask  |= 255u << shift;
    kk = sh_k;
  }
  const float thr = (__uint_as_float(prefval) / 0.6745f) * sqrtf(2.0f * logf(8192.0f));

  // iDWT2 with on-the-fly soft(a2), soft(d2): -> rec1 = A[0..4098]
  {
    const float* a2 = X;
    const float* d2 = X + 2056;
    for (int q = t; q < 1024; q += NT2) {
      const float2 a0 = reinterpret_cast<const float2*>(a2)[q];
      const float2 a1 = reinterpret_cast<const float2*>(a2)[q + 1];
      const float  a4 = a2[2 * q + 4];
      const float2 b0 = reinterpret_cast<const float2*>(d2)[q];
      const float2 b1 = reinterpret_cast<const float2*>(d2)[q + 1];
      const float  b4 = d2[2 * q + 4];
      const float w[5] = {softf(a0.x, thr), softf(a0.y, thr), softf(a1.x, thr),
                          softf(a1.y, thr), softf(a4, thr)};
      const float v[5] = {softf(b0.x, thr), softf(b0.y, thr), softf(b1.x, thr),
                          softf(b1.y, thr), softf(b4, thr)};
      reinterpret_cast<float4*>(A)[q] = idwt_quad(w, v);
    }
    if (t < 3) {   // tail outputs 4096..4098
      const int ii = 4096 + t, p = ii >> 1, oo = ii & 1;
      float acc = 0.f;
#pragma unroll
      for (int u = 0; u < 4; ++u) {
        acc = fmaf(softf(a2[p + 3 - u], thr), REC_LO[2 * u + oo], acc);
        acc = fmaf(softf(d2[p + 3 - u], thr), REC_HI[2 * u + oo], acc);
      }
      A[ii] = acc;
    }
  }
  __syncthreads();

  // iDWT1 with on-the-fly soft(d1): (rec1=A raw, D soft) -> scatter to out
  for (int q = t; q < 2048; q += NT2) {
    const float2 r0 = reinterpret_cast<const float2*>(A)[q];
    const float2 r1 = reinterpret_cast<const float2*>(A)[q + 1];
    const float  r4 = A[2 * q + 4];
    const float2 e0 = reinterpret_cast<const float2*>(D)[q];
    const float2 e1 = reinterpret_cast<const float2*>(D)[q + 1];
    const float  e4 = D[2 * q + 4];
    const float w[5] = {r0.x, r0.y, r1.x, r1.y, r4};
    const float v[5] = {softf(e0.x, thr), softf(e0.y, thr), softf(e1.x, thr),
                        softf(e1.y, thr), softf(e4, thr)};
    const float4 o = idwt_quad(w, v);
    float* p = og + (size_t)(4 * q) * 64;
    p[0] = o.x; p[64] = o.y; p[128] = o.z; p[192] = o.w;
  }
}

extern "C" void kernel_launch(void* const* d_in, const int* in_sizes, int n_in,
                              void* d_out, int out_size, void* d_ws, size_t ws_size,
                              hipStream_t stream) {
  (void)in_sizes; (void)n_in; (void)out_size; (void)d_ws; (void)ws_size;
  const float* x = (const float*)d_in[0];
  float* out = (float*)d_out;

  hipLaunchKernelGGL(k_denoise_fused, dim3(NROWS), dim3(NT2), 0, stream, x, out);
}

// Round 9
// 184.985 us; speedup vs baseline: 1.5849x; 1.5849x over previous
//
#include <hip/hip_runtime.h>

#define S0LEN 8192
#define L1LEN 4099   // (8192+7)/2
#define L2LEN 2053   // (4099+7)/2
#define NROWS 2048
#define NTT   512    // transpose kernels
#define NT2   512    // denoise kernel

// db4 filters (derived from reference _REC_LO)
constexpr float DEC_LO[8] = {
  -0.010597401784997278f,  0.032883011666982945f,  0.030841381835986965f,
  -0.18703481171888114f,  -0.02798376941698385f,   0.6308807679295904f,
   0.7148465705525415f,    0.23037781330885523f };
constexpr float DEC_HI[8] = {
  -0.23037781330885523f,   0.7148465705525415f,   -0.6308807679295904f,
  -0.02798376941698385f,   0.18703481171888114f,   0.030841381835986965f,
  -0.032883011666982945f, -0.010597401784997278f };
constexpr float REC_LO[8] = {
   0.23037781330885523f,   0.7148465705525415f,    0.6308807679295904f,
  -0.02798376941698385f,  -0.18703481171888114f,   0.030841381835986965f,
   0.032883011666982945f, -0.010597401784997278f };
constexpr float REC_HI[8] = {
  -0.010597401784997278f, -0.032883011666982945f,  0.030841381835986965f,
   0.18703481171888114f,  -0.02798376941698385f,  -0.6308807679295904f,
   0.7148465705525415f,   -0.23037781330885523f };

__device__ __forceinline__ int refl(int m, int n) {
  m = (m < 0) ? (-1 - m) : m;
  m = (m >= n) ? (2 * n - 1 - m) : m;
  return m;
}

__device__ __forceinline__ float softf(float c, float t) {
  float m = fmaxf(fabsf(c) - t, 0.0f);
  return copysignf(m, c);
}

// 4 outputs (indices 4m..4m+3 of a and d) from 14-float window src[8m-6..8m+7],
// fetched as f2(e2) + f4(e4) + f4(e4+1) + f4(e4+2). Per-output FMA order is
// identical to the scalar reference (q ascending, coeff DEC[7-q]).
__device__ __forceinline__ void dwt_quad_vec(const float* __restrict__ buf,
                                             int e2, int e4,
                                             float4& A4, float4& D4) {
  const float2 v0 = reinterpret_cast<const float2*>(buf)[e2];
  const float4 v1 = reinterpret_cast<const float4*>(buf)[e4];
  const float4 v2 = reinterpret_cast<const float4*>(buf)[e4 + 1];
  const float4 v3 = reinterpret_cast<const float4*>(buf)[e4 + 2];
  const float w[14] = {v0.x, v0.y, v1.x, v1.y, v1.z, v1.w,
                       v2.x, v2.y, v2.z, v2.w, v3.x, v3.y, v3.z, v3.w};
  float a[4], d[4];
#pragma unroll
  for (int r = 0; r < 4; ++r) {
    float aa = 0.f, dd = 0.f;
#pragma unroll
    for (int q = 0; q < 8; ++q) {
      aa = fmaf(DEC_LO[7 - q], w[2 * r + q], aa);
      dd = fmaf(DEC_HI[7 - q], w[2 * r + q], dd);
    }
    a[r] = aa; d[r] = dd;
  }
  A4 = make_float4(a[0], a[1], a[2], a[3]);
  D4 = make_float4(d[0], d[1], d[2], d[3]);
}

// scalar single output i with symmetric reflection; buf holds x[gbase..]
__device__ __forceinline__ void dwt_scalar(const float* __restrict__ buf, int gbase,
                                           int i, int n, float& a, float& d) {
  a = d = 0.f;
#pragma unroll
  for (int q = 0; q < 8; ++q) {
    const float v = buf[refl(2 * i - 6 + q, n) - gbase];
    a = fmaf(DEC_LO[7 - q], v, a);
    d = fmaf(DEC_HI[7 - q], v, d);
  }
}

// iDWT quad: outputs (4q..4q+3) from w = a[2q..2q+4], v = d[2q..2q+4]
__device__ __forceinline__ float4 idwt_quad(const float* __restrict__ w,
                                            const float* __restrict__ v) {
  float4 o; float acc;
  acc = 0.f;
#pragma unroll
  for (int u = 0; u < 4; ++u) { acc = fmaf(w[3-u], REC_LO[2*u],   acc); acc = fmaf(v[3-u], REC_HI[2*u],   acc); }
  o.x = acc;
  acc = 0.f;
#pragma unroll
  for (int u = 0; u < 4; ++u) { acc = fmaf(w[3-u], REC_LO[2*u+1], acc); acc = fmaf(v[3-u], REC_HI[2*u+1], acc); }
  o.y = acc;
  acc = 0.f;
#pragma unroll
  for (int u = 0; u < 4; ++u) { acc = fmaf(w[4-u], REC_LO[2*u],   acc); acc = fmaf(v[4-u], REC_HI[2*u],   acc); }
  o.z = acc;
  acc = 0.f;
#pragma unroll
  for (int u = 0; u < 4; ++u) { acc = fmaf(w[4-u], REC_LO[2*u+1], acc); acc = fmaf(v[4-u], REC_HI[2*u+1], acc); }
  o.w = acc;
  return o;
}

// ---- K1: x (32, 8192, 64) -> xt (2048, 8192); block = 64f x 256s tile ----
__global__ void __launch_bounds__(NTT)
k_transpose_fwd(const float* __restrict__ x, float* __restrict__ xt) {
  const int b  = blockIdx.y;
  const int s0 = blockIdx.x * 256;
  __shared__ float tile[64][256];
  const int t = threadIdx.x;
  const int lane = t & 63;
  const int wv = t >> 6;

  const float* src = x + ((size_t)b * S0LEN + s0) * 64;   // 64KB contiguous
  float4 rg[8];
#pragma unroll
  for (int k = 0; k < 8; ++k)
    rg[k] = reinterpret_cast<const float4*>(src)[t + NTT * k];
#pragma unroll
  for (int k = 0; k < 8; ++k) {
    const int n  = t + NTT * k;
    const int s  = n >> 4;          // 0..255
    const int fg = n & 15;          // float4 group along f
    const int sc = s ^ (4 * (fg & 7));
    tile[4 * fg + 0][sc] = rg[k].x;
    tile[4 * fg + 1][sc] = rg[k].y;
    tile[4 * fg + 2][sc] = rg[k].z;
    tile[4 * fg + 3][sc] = rg[k].w;
  }
  __syncthreads();
#pragma unroll
  for (int j = 0; j < 8; ++j) {
    const int f = 8 * wv + j;
    const int swz = 4 * ((f >> 2) & 7);
    const float4 v = *reinterpret_cast<const float4*>(&tile[f][(4 * lane) ^ swz]);
    reinterpret_cast<float4*>(xt + (size_t)(b * 64 + f) * S0LEN + s0)[lane] = v;
  }
}

// ---- K2: per-row denoise, in place on ws row; 3 blocks/CU ----
__global__ void __launch_bounds__(NT2, 6)
k_denoise(float* __restrict__ ws) {
  const int r = blockIdx.x;
  float* row = ws + (size_t)r * S0LEN;

  __shared__ alignas(16) float X[4112];   // x chunk; later a2[0..2052] | d2 @2056..4108
  __shared__ alignas(16) float A[4100];   // a1; median-hist scratch; later rec1[0..4098]
  __shared__ alignas(16) float D[4100];   // d1 (raw; soft applied on the fly)
  const int t = threadIdx.x;

  unsigned myu[8];   // |d1| bit patterns this thread produced (compile-time indexed)
  unsigned exU[3];   // thread-0 extras (d1[4096..4098])

  // chunk0 load: x[0..4107]
  {
    const float4* s4 = reinterpret_cast<const float4*>(row);
    float4* d4 = reinterpret_cast<float4*>(X);
    for (int j = t; j < 1027; j += NT2) d4[j] = s4[j];
  }
  __syncthreads();

  // DWT1 chunk0: thread t -> outputs 4t..4t+3 (pairs 2t, 2t+1)
  {
    float4 a4, d4;
    if (t >= 1) {
      dwt_quad_vec(X, 4 * t - 3, 2 * t - 1, a4, d4);
    } else {
      float av[4], dv[4];
#pragma unroll
      for (int i = 0; i < 4; ++i) dwt_scalar(X, 0, i, S0LEN, av[i], dv[i]);
      a4 = make_float4(av[0], av[1], av[2], av[3]);
      d4 = make_float4(dv[0], dv[1], dv[2], dv[3]);
    }
    reinterpret_cast<float4*>(A)[t] = a4;
    reinterpret_cast<float4*>(D)[t] = d4;
    myu[0] = __float_as_uint(fabsf(d4.x)); myu[1] = __float_as_uint(fabsf(d4.y));
    myu[2] = __float_as_uint(fabsf(d4.z)); myu[3] = __float_as_uint(fabsf(d4.w));
  }
  __syncthreads();

  // chunk1 load: x[4088..8191] -> X[0..4103]  (base 4088 keeps b128 alignment)
  {
    const float4* s4 = reinterpret_cast<const float4*>(row) + 1022;
    float4* d4 = reinterpret_cast<float4*>(X);
    for (int j = t; j < 1026; j += NT2) d4[j] = s4[j];
  }
  __syncthreads();

  // DWT1 chunk1: thread t -> outputs 2048+4t..2048+4t+3 (pairs 1024+2t, 1024+2t+1)
  // window x[4090+8t..4103+8t] -> local [8t+2..8t+15]: f2(4t+1), f4(2t+1..2t+3)
  {
    float4 a4, d4;
    dwt_quad_vec(X, 4 * t + 1, 2 * t + 1, a4, d4);
    reinterpret_cast<float4*>(A)[512 + t] = a4;
    reinterpret_cast<float4*>(D)[512 + t] = d4;
    myu[4] = __float_as_uint(fabsf(d4.x)); myu[5] = __float_as_uint(fabsf(d4.y));
    myu[6] = __float_as_uint(fabsf(d4.z)); myu[7] = __float_as_uint(fabsf(d4.w));
    if (t == 0) {   // tail outputs 4096..4098 (reflective)
#pragma unroll
      for (int i = 0; i < 3; ++i) {
        float av, dv;
        dwt_scalar(X, 4088, 4096 + i, S0LEN, av, dv);
        A[4096 + i] = av; D[4096 + i] = dv;
        exU[i] = __float_as_uint(fabsf(dv));
      }
    }
  }
  __syncthreads();

  // DWT2: A(4099) -> a2 = X[0..2052], d2 = X[2056..4108]
  // thread t -> outputs 4t..4t+3 (vector for 1<=t<=511); thread 1 also does 2048..2052
  {
    float4 a4, d4;
    if (t >= 1) {
      dwt_quad_vec(A, 4 * t - 3, 2 * t - 1, a4, d4);
    } else {
      float av[4], dv[4];
#pragma unroll
      for (int i = 0; i < 4; ++i) dwt_scalar(A, 0, i, L1LEN, av[i], dv[i]);
      a4 = make_float4(av[0], av[1], av[2], av[3]);
      d4 = make_float4(dv[0], dv[1], dv[2], dv[3]);
    }
    reinterpret_cast<float4*>(X)[t] = a4;
    reinterpret_cast<float4*>(X)[514 + t] = d4;    // 2056/4 = 514
    if (t == 1) {
      for (int i = 2048; i <= 2052; ++i) {
        float av, dv;
        dwt_scalar(A, 0, i, L1LEN, av, dv);
        X[i] = av; X[2056 + i] = dv;
      }
    }
  }
  __syncthreads();

  // exact median of |d1| (4099 elems, 0-indexed rank 2049), 4x radix-256 select.
  // 8 per-wave private histograms aliased onto A (a1 dead); values from registers.
  unsigned* H = reinterpret_cast<unsigned*>(A);
  unsigned prefval = 0u, himask = 0u;
  int kk = 2049;
  for (int pass = 0; pass < 4; ++pass) {
    const int shift = 24 - 8 * pass;
    reinterpret_cast<uint4*>(H)[t] = make_uint4(0u, 0u, 0u, 0u);   // zero 2048 bins
    __syncthreads();
    unsigned* myh = H + ((t >> 6) << 8);
#pragma unroll
    for (int s = 0; s < 8; ++s) {
      const unsigned u = myu[s];
      if ((u & himask) == prefval) atomicAdd(&myh[(u >> shift) & 255u], 1u);
    }
    if (t == 0) {
#pragma unroll
      for (int s = 0; s < 3; ++s) {
        const unsigned u = exU[s];
        if ((u & himask) == prefval) atomicAdd(&myh[(u >> shift) & 255u], 1u);
      }
    }
    __syncthreads();
    unsigned c = 0u, incl = 0u;
    if (t < 256) {
#pragma unroll
      for (int w = 0; w < 8; ++w) c += H[(w << 8) + t];
      incl = c;
#pragma unroll
      for (int dlt = 1; dlt < 64; dlt <<= 1) {
        const unsigned nn = __shfl_up(incl, dlt, 64);
        if ((t & 63) >= dlt) incl += nn;
      }
      if ((t & 63) == 63) H[2048 + (t >> 6)] = incl;
    }
    __syncthreads();
    if (t < 256) {
      unsigned base = 0u;
      for (int w = 0; w < (t >> 6); ++w) base += H[2048 + w];
      incl += base;
      if ((unsigned)kk < incl && (unsigned)kk >= incl - c) {
        H[2052] = (unsigned)t;
        H[2053] = (unsigned)(kk - (int)(incl - c));
      }
    }
    __syncthreads();
    prefval |= H[2052] << shift;
    himask  |= 255u << shift;
    kk = (int)H[2053];
  }
  const float thr = (__uint_as_float(prefval) / 0.6745f) * sqrtf(2.0f * logf(8192.0f));
  __syncthreads();   // protect H reads before A is overwritten with rec1

  // iDWT2 with on-the-fly soft: thread t -> rec1 outputs 8t..8t+7; tail 4096..4098
  {
    const float* a2 = X;
    const float* d2 = X + 2056;
    const float4 wa0 = reinterpret_cast<const float4*>(a2)[t];
    const float4 wa1 = reinterpret_cast<const float4*>(a2)[t + 1];
    const float4 wd0 = reinterpret_cast<const float4*>(d2)[t];
    const float4 wd1 = reinterpret_cast<const float4*>(d2)[t + 1];
    const float w[7] = {softf(wa0.x, thr), softf(wa0.y, thr), softf(wa0.z, thr),
                        softf(wa0.w, thr), softf(wa1.x, thr), softf(wa1.y, thr),
                        softf(wa1.z, thr)};
    const float v[7] = {softf(wd0.x, thr), softf(wd0.y, thr), softf(wd0.z, thr),
                        softf(wd0.w, thr), softf(wd1.x, thr), softf(wd1.y, thr),
                        softf(wd1.z, thr)};
    const float4 o0 = idwt_quad(w, v);          // outputs 8t..8t+3
    const float4 o1 = idwt_quad(w + 2, v + 2);  // outputs 8t+4..8t+7
    float tv = 0.f;
    if (t < 3) {   // compute tail before any rec1 writes land (barrier below orders)
      const int i = 4096 + t, p = i >> 1, oo = i & 1;
      float acc = 0.f;
#pragma unroll
      for (int u = 0; u < 4; ++u) {
        acc = fmaf(softf(a2[p + 3 - u], thr), REC_LO[2 * u + oo], acc);
        acc = fmaf(softf(d2[p + 3 - u], thr), REC_HI[2 * u + oo], acc);
      }
      tv = acc;
    }
    reinterpret_cast<float4*>(A)[2 * t]     = o0;
    reinterpret_cast<float4*>(A)[2 * t + 1] = o1;
    if (t < 3) A[4096 + t] = tv;
  }
  __syncthreads();

  // iDWT1 with on-the-fly soft(d1): thread t -> outputs 8m..8m+7 for m = t, t+512
#pragma unroll
  for (int mm = 0; mm < 2; ++mm) {
    const int m = t + mm * 512;
    const float4 wa0 = reinterpret_cast<const float4*>(A)[m];
    const float4 wa1 = reinterpret_cast<const float4*>(A)[m + 1];
    const float4 wd0 = reinterpret_cast<const float4*>(D)[m];
    const float4 wd1 = reinterpret_cast<const float4*>(D)[m + 1];
    const float w[7] = {wa0.x, wa0.y, wa0.z, wa0.w, wa1.x, wa1.y, wa1.z};
    const float v[7] = {softf(wd0.x, thr), softf(wd0.y, thr), softf(wd0.z, thr),
                        softf(wd0.w, thr), softf(wd1.x, thr), softf(wd1.y, thr),
                        softf(wd1.z, thr)};
    reinterpret_cast<float4*>(row)[2 * m]     = idwt_quad(w, v);
    reinterpret_cast<float4*>(row)[2 * m + 1] = idwt_quad(w + 2, v + 2);
  }
}

// ---- K3: xt (2048, 8192) -> out (32, 8192, 64); mirror of K1 ----
__global__ void __launch_bounds__(NTT)
k_transpose_bwd(const float* __restrict__ xt, float* __restrict__ out) {
  const int b  = blockIdx.y;
  const int s0 = blockIdx.x * 256;
  __shared__ float tile[64][256];
  const int t = threadIdx.x;
  const int lane = t & 63;
  const int wv = t >> 6;

#pragma unroll
  for (int j = 0; j < 8; ++j) {
    const int f = 8 * wv + j;
    const int swz = 4 * ((f >> 2) & 7);
    const float4 v = reinterpret_cast<const float4*>(xt + (size_t)(b * 64 + f) * S0LEN + s0)[lane];
    *reinterpret_cast<float4*>(&tile[f][(4 * lane) ^ swz]) = v;
  }
  __syncthreads();

  float* dst = out + ((size_t)b * S0LEN + s0) * 64;   // 64KB contiguous
#pragma unroll
  for (int k = 0; k < 8; ++k) {
    const int n  = t + NTT * k;
    const int s  = n >> 4;
    const int fg = n & 15;
    const int sc = s ^ (4 * (fg & 7));
    float4 v;
    v.x = tile[4 * fg + 0][sc];
    v.y = tile[4 * fg + 1][sc];
    v.z = tile[4 * fg + 2][sc];
    v.w = tile[4 * fg + 3][sc];
    reinterpret_cast<float4*>(dst)[n] = v;
  }
}

extern "C" void kernel_launch(void* const* d_in, const int* in_sizes, int n_in,
                              void* d_out, int out_size, void* d_ws, size_t ws_size,
                              hipStream_t stream) {
  (void)in_sizes; (void)n_in; (void)out_size; (void)ws_size;
  const float* x = (const float*)d_in[0];
  float* out = (float*)d_out;
  float* ws  = (float*)d_ws;   // needs 2048*8192*4 = 64 MB

  const dim3 gT(S0LEN / 256, 32);
  hipLaunchKernelGGL(k_transpose_fwd, gT, dim3(NTT), 0, stream, x, ws);
  hipLaunchKernelGGL(k_denoise, dim3(NROWS), dim3(NT2), 0, stream, ws);
  hipLaunchKernelGGL(k_transpose_bwd, gT, dim3(NTT), 0, stream, ws, out);
}